// Round 4
// baseline (46.513 us; speedup 1.0000x reference)
//
#include <hip/hip_runtime.h>

// 3x3 median filter, stride 1, reflect padding ("same"), NCHW fp32.
// Input: 32 x 3 x 512 x 512 fp32. Output: same shape.
//
// Each thread computes an 8-row x 8-col output patch:
//   - 20 float4 loads (10 input rows) + 16 nt stores = 36 VMEM / 64 outputs
//   - vertical fetch redundancy 10/8 = 1.25x (was 1.5x)
//   - 20 loads in flight per thread -> more MLP vs round 3's 12
//   - horizontal edge taps via shfl (wave's 64 lanes = one 512-wide row),
//     reflect at lane 0/63.
//   - separable median-of-9: column sort3 (v_min3/v_med3/v_max3) then
//     med3(max3(lo), med3(mi), min3(hi)).
//   - nontemporal stores: output has no reuse; keep input resident in L2/L3.

#define IMG_H 512
#define IMG_W 512

__device__ __forceinline__ float min3f(float a, float b, float c) {
    return fminf(fminf(a, b), c);
}
__device__ __forceinline__ float max3f(float a, float b, float c) {
    return fmaxf(fmaxf(a, b), c);
}
__device__ __forceinline__ float med3f(float a, float b, float c) {
    return __builtin_amdgcn_fmed3f(a, b, c);   // v_med3_f32
}

__device__ __forceinline__ void nt_store4(float* p, float4 v) {
    __builtin_nontemporal_store(v.x, p);
    __builtin_nontemporal_store(v.y, p + 1);
    __builtin_nontemporal_store(v.z, p + 2);
    __builtin_nontemporal_store(v.w, p + 3);
}

__global__ __launch_bounds__(256, 4) void median3x3_kernel(
        const float* __restrict__ in, float* __restrict__ out, int nplanes) {
    const int lane = threadIdx.x & 63;
    const int rowgroup = blockIdx.x * 4 + (threadIdx.x >> 6); // 8-row stripe
    const int plane = rowgroup >> 6;                          // /(512/8)
    const int y0 = (rowgroup & 63) * 8;                       // first out row
    const int x0 = lane * 8;                                  // first out col
    if (plane >= nplanes) return;

    const size_t pbase = (size_t)plane * IMG_H * IMG_W;
    const float* bp = in + pbase;

    // 10 source rows y0-1 .. y0+8 with reflect at the image border
    int ys[10];
    ys[0] = (y0 == 0) ? 1 : y0 - 1;
#pragma unroll
    for (int k = 1; k <= 8; ++k) ys[k] = y0 + k - 1;
    ys[9] = (y0 + 8 == IMG_H) ? IMG_H - 2 : y0 + 8;

    // issue all 20 vector loads up front
    float4 v0[10], v1[10];
#pragma unroll
    for (int k = 0; k < 10; ++k) {
        const float* r = bp + (size_t)ys[k] * IMG_W + x0;
        v0[k] = *reinterpret_cast<const float4*>(r);
        v1[k] = *reinterpret_cast<const float4*>(r + 4);
    }

    // horizontal edge taps from neighbor lanes (reflect at row ends)
    float L[10], R[10];
#pragma unroll
    for (int k = 0; k < 10; ++k) {
        float l  = __shfl_up(v1[k].w, 1);    // lane-1's col x0+7 (= col x0-1)
        float rr = __shfl_down(v0[k].x, 1);  // lane+1's col x0   (= col x0+8)
        L[k] = (lane == 0)  ? v0[k].y : l;   // reflect(-1)  = col 1
        R[k] = (lane == 63) ? v1[k].z : rr;  // reflect(512) = col 510
    }

    float* op = out + pbase + (size_t)y0 * IMG_W + x0;
#pragma unroll
    for (int w = 0; w < 8; ++w) {
        const float A[10] = {L[w],      v0[w].x,   v0[w].y,   v0[w].z,   v0[w].w,
                             v1[w].x,   v1[w].y,   v1[w].z,   v1[w].w,   R[w]};
        const float B[10] = {L[w+1],    v0[w+1].x, v0[w+1].y, v0[w+1].z, v0[w+1].w,
                             v1[w+1].x, v1[w+1].y, v1[w+1].z, v1[w+1].w, R[w+1]};
        const float C[10] = {L[w+2],    v0[w+2].x, v0[w+2].y, v0[w+2].z, v0[w+2].w,
                             v1[w+2].x, v1[w+2].y, v1[w+2].z, v1[w+2].w, R[w+2]};

        float lo[10], mi[10], hi[10];
#pragma unroll
        for (int i = 0; i < 10; ++i) {
            lo[i] = min3f(A[i], B[i], C[i]);
            mi[i] = med3f(A[i], B[i], C[i]);
            hi[i] = max3f(A[i], B[i], C[i]);
        }
        float o[8];
#pragma unroll
        for (int i = 0; i < 8; ++i) {
            o[i] = med3f(max3f(lo[i], lo[i + 1], lo[i + 2]),
                         med3f(mi[i], mi[i + 1], mi[i + 2]),
                         min3f(hi[i], hi[i + 1], hi[i + 2]));
        }
        nt_store4(op + (size_t)w * IMG_W,     make_float4(o[0], o[1], o[2], o[3]));
        nt_store4(op + (size_t)w * IMG_W + 4, make_float4(o[4], o[5], o[6], o[7]));
    }
}

extern "C" void kernel_launch(void* const* d_in, const int* in_sizes, int n_in,
                              void* d_out, int out_size, void* d_ws, size_t ws_size,
                              hipStream_t stream) {
    const float* x = (const float*)d_in[0];
    float* out = (float*)d_out;
    int nplanes = in_sizes[0] / (IMG_H * IMG_W);           // 32*3 = 96

    // one wave (64 lanes) per 8-row stripe; 4 waves per block
    int rowgroups = nplanes * (IMG_H / 8);                 // 6,144
    int grid = rowgroups / 4;                              // 1,536 blocks
    median3x3_kernel<<<grid, 256, 0, stream>>>(x, out, nplanes);
}

// Round 5
// 34.748 us; speedup vs baseline: 1.3386x; 1.3386x over previous
//
#include <hip/hip_runtime.h>

// 3x3 median filter, stride 1, reflect padding ("same"), NCHW fp32.
// Input: 32 x 3 x 512 x 512 fp32. Output: same shape.
//
// Latency-bound regime (R1-R4 evidence: VALUBusy <13%, HBM <50% peak,
// occupancy 50-75%). This round: maximize wave count for latency hiding.
//   - one wave per 2-row x 512-col stripe: 8 float4 loads + 4 float4 stores
//     per thread (0.75 VMEM/output), 24576 waves = 3x the 8192 wave slots.
//   - plain vector stores (R4's per-component nontemporal stores quadrupled
//     store instructions and raised WRITE_SIZE 98->115 MB).
//   - XCD-aware block swizzle: consecutive stripes (sharing 2 input rows)
//     land on the same XCD's L2. 6144 blocks % 8 == 0 -> bijective.
//   - separable median-of-9: column sort3 (v_min3/v_med3/v_max3) then
//     med3(max3(lo), med3(mi), min3(hi)); horizontal taps via shfl.

#define IMG_H 512
#define IMG_W 512
#define NXCD 8

__device__ __forceinline__ float min3f(float a, float b, float c) {
    return fminf(fminf(a, b), c);
}
__device__ __forceinline__ float max3f(float a, float b, float c) {
    return fmaxf(fmaxf(a, b), c);
}
__device__ __forceinline__ float med3f(float a, float b, float c) {
    return __builtin_amdgcn_fmed3f(a, b, c);   // v_med3_f32
}

__global__ __launch_bounds__(256) void median3x3_kernel(
        const float* __restrict__ in, float* __restrict__ out,
        int nplanes, int blocks_per_xcd) {
    // XCD swizzle: blocks with equal (blockIdx.x % 8) run on the same XCD;
    // give them contiguous stripe ranges for L2 row-overlap reuse.
    int bid = (int)blockIdx.x;
    int sbid = (bid & (NXCD - 1)) * blocks_per_xcd + (bid >> 3);

    const int lane = threadIdx.x & 63;
    const int stripe = sbid * 4 + (threadIdx.x >> 6);   // 2-row stripe
    const int plane = stripe >> 8;                      // 256 stripes/plane
    const int y0 = (stripe & 255) * 2;                  // first out row
    const int x0 = lane * 8;                            // first out col
    if (plane >= nplanes) return;

    const size_t pbase = (size_t)plane * IMG_H * IMG_W;
    const float* bp = in + pbase;

    // 4 source rows y0-1 .. y0+2 with reflect at the image border
    int ys[4];
    ys[0] = (y0 == 0) ? 1 : y0 - 1;
    ys[1] = y0;
    ys[2] = y0 + 1;
    ys[3] = (y0 + 2 == IMG_H) ? IMG_H - 2 : y0 + 2;

    // issue all 8 vector loads up front
    float4 v0[4], v1[4];
#pragma unroll
    for (int k = 0; k < 4; ++k) {
        const float* r = bp + (size_t)ys[k] * IMG_W + x0;
        v0[k] = *reinterpret_cast<const float4*>(r);
        v1[k] = *reinterpret_cast<const float4*>(r + 4);
    }

    // horizontal edge taps from neighbor lanes (reflect at row ends)
    float L[4], R[4];
#pragma unroll
    for (int k = 0; k < 4; ++k) {
        float l  = __shfl_up(v1[k].w, 1);    // lane-1's col x0+7 (= col x0-1)
        float rr = __shfl_down(v0[k].x, 1);  // lane+1's col x0   (= col x0+8)
        L[k] = (lane == 0)  ? v0[k].y : l;   // reflect(-1)  = col 1
        R[k] = (lane == 63) ? v1[k].z : rr;  // reflect(512) = col 510
    }

    float* op = out + pbase + (size_t)y0 * IMG_W + x0;
#pragma unroll
    for (int w = 0; w < 2; ++w) {
        const float A[10] = {L[w],      v0[w].x,   v0[w].y,   v0[w].z,   v0[w].w,
                             v1[w].x,   v1[w].y,   v1[w].z,   v1[w].w,   R[w]};
        const float B[10] = {L[w+1],    v0[w+1].x, v0[w+1].y, v0[w+1].z, v0[w+1].w,
                             v1[w+1].x, v1[w+1].y, v1[w+1].z, v1[w+1].w, R[w+1]};
        const float C[10] = {L[w+2],    v0[w+2].x, v0[w+2].y, v0[w+2].z, v0[w+2].w,
                             v1[w+2].x, v1[w+2].y, v1[w+2].z, v1[w+2].w, R[w+2]};

        float lo[10], mi[10], hi[10];
#pragma unroll
        for (int i = 0; i < 10; ++i) {
            lo[i] = min3f(A[i], B[i], C[i]);
            mi[i] = med3f(A[i], B[i], C[i]);
            hi[i] = max3f(A[i], B[i], C[i]);
        }
        float o[8];
#pragma unroll
        for (int i = 0; i < 8; ++i) {
            o[i] = med3f(max3f(lo[i], lo[i + 1], lo[i + 2]),
                         med3f(mi[i], mi[i + 1], mi[i + 2]),
                         min3f(hi[i], hi[i + 1], hi[i + 2]));
        }
        *reinterpret_cast<float4*>(op + (size_t)w * IMG_W)
            = make_float4(o[0], o[1], o[2], o[3]);
        *reinterpret_cast<float4*>(op + (size_t)w * IMG_W + 4)
            = make_float4(o[4], o[5], o[6], o[7]);
    }
}

extern "C" void kernel_launch(void* const* d_in, const int* in_sizes, int n_in,
                              void* d_out, int out_size, void* d_ws, size_t ws_size,
                              hipStream_t stream) {
    const float* x = (const float*)d_in[0];
    float* out = (float*)d_out;
    int nplanes = in_sizes[0] / (IMG_H * IMG_W);            // 32*3 = 96

    // one wave per 2-row stripe; 4 waves per block
    int stripes = nplanes * (IMG_H / 2);                    // 24,576
    int grid = stripes / 4;                                 // 6,144 blocks
    int blocks_per_xcd = grid / NXCD;                       // 768
    median3x3_kernel<<<grid, 256, 0, stream>>>(x, out, nplanes, blocks_per_xcd);
}

// Round 6
// 33.677 us; speedup vs baseline: 1.3811x; 1.0318x over previous
//
#include <hip/hip_runtime.h>

// 3x3 median filter, stride 1, reflect padding ("same"), NCHW fp32.
// Input: 32 x 3 x 512 x 512 fp32. Output: same shape.
//
// Latency-bound regime (R1-R5 evidence). R5 (2-row stripes, 24576 waves,
// XCD swizzle) -> 34.7us. This round: 1-row stripes -> 49152 waves (6x the
// 8192 wave slots), halving per-wave dependent-chain length and the tail.
// Read redundancy 3x is absorbed by L2/L3 (R5 showed FETCH stays ~50MB).
//   - per thread: 6 float4 loads (3 rows), 2 float4 stores, 8 outputs.
//   - horizontal edge taps via shfl (wave's 64 lanes = one 512-wide row),
//     reflect at lane 0/63.
//   - separable median-of-9: column sort3 (v_min3/v_med3/v_max3) then
//     med3(max3(lo), med3(mi), min3(hi)).
//   - XCD-aware block swizzle keeps vertically-adjacent stripes on-XCD.

#define IMG_H 512
#define IMG_W 512
#define NXCD 8

__device__ __forceinline__ float min3f(float a, float b, float c) {
    return fminf(fminf(a, b), c);
}
__device__ __forceinline__ float max3f(float a, float b, float c) {
    return fmaxf(fmaxf(a, b), c);
}
__device__ __forceinline__ float med3f(float a, float b, float c) {
    return __builtin_amdgcn_fmed3f(a, b, c);   // v_med3_f32
}

__global__ __launch_bounds__(256) void median3x3_kernel(
        const float* __restrict__ in, float* __restrict__ out,
        int nplanes, int blocks_per_xcd) {
    // XCD swizzle: blocks with equal (blockIdx.x % 8) run on the same XCD;
    // give them contiguous row ranges for L2 row-overlap reuse.
    int bid = (int)blockIdx.x;
    int sbid = (bid & (NXCD - 1)) * blocks_per_xcd + (bid >> 3);

    const int lane = threadIdx.x & 63;
    const int row = sbid * 4 + (threadIdx.x >> 6);      // one output row
    const int plane = row >> 9;                         // / 512
    const int y = row & (IMG_H - 1);
    const int x0 = lane * 8;                            // first of 8 out cols
    if (plane >= nplanes) return;

    const size_t pbase = (size_t)plane * IMG_H * IMG_W;
    const float* bp = in + pbase;

    // reflect-pad row indices (pad=1): -1 -> 1, H -> H-2
    int ym = (y == 0)         ? 1         : y - 1;
    int yp = (y == IMG_H - 1) ? IMG_H - 2 : y + 1;
    const float* r0 = bp + (size_t)ym * IMG_W + x0;
    const float* r1 = bp + (size_t)y  * IMG_W + x0;
    const float* r2 = bp + (size_t)yp * IMG_W + x0;

    // 6 vector loads issued up front
    float4 a0 = *reinterpret_cast<const float4*>(r0);
    float4 a1 = *reinterpret_cast<const float4*>(r0 + 4);
    float4 b0 = *reinterpret_cast<const float4*>(r1);
    float4 b1 = *reinterpret_cast<const float4*>(r1 + 4);
    float4 c0 = *reinterpret_cast<const float4*>(r2);
    float4 c1 = *reinterpret_cast<const float4*>(r2 + 4);

    // horizontal edge taps from neighbor lanes (reflect at row ends)
    float aL = __shfl_up(a1.w, 1), aR = __shfl_down(a0.x, 1);
    float bL = __shfl_up(b1.w, 1), bR = __shfl_down(b0.x, 1);
    float cL = __shfl_up(c1.w, 1), cR = __shfl_down(c0.x, 1);
    if (lane == 0)  { aL = a0.y; bL = b0.y; cL = c0.y; }   // reflect(-1)=col 1
    if (lane == 63) { aR = a1.z; bR = b1.z; cR = c1.z; }   // reflect(512)=510

    const float A[10] = {aL, a0.x, a0.y, a0.z, a0.w, a1.x, a1.y, a1.z, a1.w, aR};
    const float B[10] = {bL, b0.x, b0.y, b0.z, b0.w, b1.x, b1.y, b1.z, b1.w, bR};
    const float C[10] = {cL, c0.x, c0.y, c0.z, c0.w, c1.x, c1.y, c1.z, c1.w, cR};

    float lo[10], mi[10], hi[10];
#pragma unroll
    for (int i = 0; i < 10; ++i) {
        lo[i] = min3f(A[i], B[i], C[i]);
        mi[i] = med3f(A[i], B[i], C[i]);
        hi[i] = max3f(A[i], B[i], C[i]);
    }
    float o[8];
#pragma unroll
    for (int i = 0; i < 8; ++i) {
        o[i] = med3f(max3f(lo[i], lo[i + 1], lo[i + 2]),
                     med3f(mi[i], mi[i + 1], mi[i + 2]),
                     min3f(hi[i], hi[i + 1], hi[i + 2]));
    }

    float* op = out + pbase + (size_t)y * IMG_W + x0;
    *reinterpret_cast<float4*>(op)     = make_float4(o[0], o[1], o[2], o[3]);
    *reinterpret_cast<float4*>(op + 4) = make_float4(o[4], o[5], o[6], o[7]);
}

extern "C" void kernel_launch(void* const* d_in, const int* in_sizes, int n_in,
                              void* d_out, int out_size, void* d_ws, size_t ws_size,
                              hipStream_t stream) {
    const float* x = (const float*)d_in[0];
    float* out = (float*)d_out;
    int nplanes = in_sizes[0] / (IMG_H * IMG_W);            // 32*3 = 96

    // one wave per output row; 4 waves per block
    int rows = nplanes * IMG_H;                             // 49,152
    int grid = rows / 4;                                    // 12,288 blocks
    int blocks_per_xcd = grid / NXCD;                       // 1,536
    median3x3_kernel<<<grid, 256, 0, stream>>>(x, out, nplanes, blocks_per_xcd);
}